// Round 13
// baseline (1083.598 us; speedup 1.0000x reference)
//
#include <hip/hip_runtime.h>
#include <hip/hip_bf16.h>

#define B_ 8
#define L_ 4096
#define H_ 256
#define NH_ 4
#define DI_ 1024
#define NL_ 6
#define TOK_ (B_*L_)

typedef unsigned short u16;
typedef __attribute__((ext_vector_type(8))) short short8;
typedef __attribute__((ext_vector_type(4))) float f32x4;

struct __align__(8) u16x4 { u16 x,y,z,w; };

__device__ __forceinline__ float bf2f(u16 u){
  union { unsigned u; float f; } c; c.u = ((unsigned)u)<<16; return c.f;
}
__device__ __forceinline__ u16 f2bf(float f){
  union { float f; unsigned u; } c; c.f = f;
  unsigned r = c.u + 0x7FFF + ((c.u>>16)&1);
  return (u16)(r>>16);
}
__device__ __forceinline__ void gload_lds16(const short* g, short* l){
  __builtin_amdgcn_global_load_lds(
      (const __attribute__((address_space(1))) void*)g,
      (__attribute__((address_space(3))) void*)l, 16, 0, 0);
}
// raw block barrier WITHOUT the vmcnt(0) drain __syncthreads would emit.
__device__ __forceinline__ void block_sync(){
  asm volatile("" ::: "memory");
  __builtin_amdgcn_s_barrier();
  __builtin_amdgcn_sched_barrier(0);
}
#define WAIT_VMCNT(N) asm volatile("s_waitcnt vmcnt(" #N ")" ::: "memory")
#define WAIT_LGKM0()  asm volatile("s_waitcnt lgkmcnt(0)" ::: "memory")

// ---------------- bf16 MFMA GEMM: out[M,N] = A[M,K] @ W[N,K]^T + bias ----------------
// BM=BN=128, BK=64, 512 threads (8 waves of 32x64 out), double-buffered LDS,
// counted-vmcnt depth-2. LDS 64KB -> 2 blocks/CU x 8 waves = 16 waves/CU (4/SIMD).
// 1-D grid nbn*256; XCD decode: each XCD owns a contiguous 32-M-tile range.
template<bool RELU, bool OBF16>
__global__ __launch_bounds__(512, 4) void gemm_bt(
    const u16* __restrict__ A, const u16* __restrict__ W,
    const float* __restrict__ bias, void* __restrict__ out, int N, int K, int nbn)
{
  constexpr int BM=128, BK=64;
  __shared__ __align__(16) short As[2][BM*BK];   // 2 x 16 KB
  __shared__ __align__(16) short Ws[2][BM*BK];   // 2 x 16 KB
  const int tid = threadIdx.x, lane = tid&63, wid = tid>>6;   // wid 0..7
  const int wm = wid>>1, wn = wid&1;   // wm: 32-row band, wn: 64-col half
  const int id = blockIdx.x;
  const int xcd = id & 7, j = id >> 3;
  const int bm = xcd*32 + j / nbn;
  const int bn = j % nbn;
  const short* Ag = (const short*)A + (size_t)bm*BM*K;
  const short* Wg = (const short*)W + (size_t)bn*BM*K;
  f32x4 acc[2][4] = {};

  auto STAGE = [&](int k0, int buf){   // 4 global_load_lds per thread (2 A + 2 W)
    #pragma unroll
    for (int jj=0;jj<2;++jj){
      int c = jj*512 + tid;            // 16B-chunk index 0..1023
      int row = c>>3;
      int col = (c&7) ^ (row&7);
      const size_t src = (size_t)row*K + k0 + col*8;
      gload_lds16(Ag + src, &As[buf][(size_t)c*8]);
      gload_lds16(Wg + src, &Ws[buf][(size_t)c*8]);
    }
  };
  auto COMPUTE = [&](int cur){
    #pragma unroll
    for (int kk=0;kk<BK;kk+=32){
      short8 af[2], bfr[4];
      int kc = (kk>>3) + (lane>>4);
      #pragma unroll
      for (int ms=0;ms<2;++ms){
        int r = wm*32 + ms*16 + (lane&15);
        af[ms] = *(const short8*)&As[cur][r*BK + ((kc ^ (r&7))<<3)];
      }
      #pragma unroll
      for (int ns=0;ns<4;++ns){
        int r = wn*64 + ns*16 + (lane&15);
        bfr[ns] = *(const short8*)&Ws[cur][r*BK + ((kc ^ (r&7))<<3)];
      }
      #pragma unroll
      for (int ms=0;ms<2;++ms)
        #pragma unroll
        for (int ns=0;ns<4;++ns)
          acc[ms][ns] = __builtin_amdgcn_mfma_f32_16x16x32_bf16(af[ms], bfr[ns], acc[ms][ns], 0, 0, 0);
    }
  };

  const int NT = K/BK;              // >= 2 for all call sites (K=256)
  STAGE(0, 0); STAGE(BK, 1);
  WAIT_VMCNT(4);                    // t0 complete; t1's 4 stay in flight
  block_sync();
  for (int t=0;t<NT;++t){
    const int cur = t&1;
    __builtin_amdgcn_s_setprio(1);
    COMPUTE(cur);
    __builtin_amdgcn_s_setprio(0);
    block_sync();                   // all waves done reading buf cur
    if (t+2 < NT) STAGE((t+2)*BK, cur);
    if (t+1 < NT){
      if (t+2 < NT) { WAIT_VMCNT(4); }   // complete t+1, keep t+2 in flight
      else          { WAIT_VMCNT(0); }   // tail
      block_sync();
    }
  }
  // ---- epilogue: bias (+relu) -> LDS restage -> coalesced 16B/lane stores ----
  if (OBF16){
    constexpr int OP = 136;         // padded LDS row stride (u16) to break bank alias
    u16* O = (u16*)&As[0][0];       // 128*136*2 = 34816 B over dead As(+head of Ws)
    #pragma unroll
    for (int ns=0;ns<4;++ns){
      int lc = wn*64 + ns*16 + (lane&15);
      float bc = bias[bn*BM + lc];
      #pragma unroll
      for (int ms=0;ms<2;++ms){
        int rbase = wm*32 + ms*16 + ((lane>>4)<<2);
        #pragma unroll
        for (int i=0;i<4;++i){
          float v = acc[ms][ns][i] + bc;
          if (RELU) v = fmaxf(v, 0.f);
          O[(rbase+i)*OP + lc] = f2bf(v);
        }
      }
    }
    block_sync();
    u16* ob = (u16*)out + (size_t)bm*BM*N + bn*BM;
    const int rr = tid>>4;          // 16 threads/row, 32 rows/pass
    const int cc = (tid&15)<<3;     // 8 u16 = 16 B per thread
    #pragma unroll
    for (int p=0;p<4;++p){
      int r = p*32 + rr;
      *reinterpret_cast<short8*>(ob + (size_t)r*N + cc) =
          *reinterpret_cast<const short8*>(&O[r*OP + cc]);
    }
  } else {
    const int r0 = bm*BM + wm*32;
    const int c0 = bn*BM + wn*64;
    #pragma unroll
    for (int ns=0;ns<4;++ns){
      int col = c0 + ns*16 + (lane&15);
      float bc = bias[col];
      #pragma unroll
      for (int ms=0;ms<2;++ms){
        int rbase = r0 + ms*16 + ((lane>>4)<<2);
        #pragma unroll
        for (int i=0;i<4;++i){
          float v = acc[ms][ns][i] + bc;
          if (RELU) v = fmaxf(v, 0.f);
          ((float*)out)[(size_t)(rbase+i)*N + col] = v;
        }
      }
    }
  }
}

// ------------- GEMM (N=256 full) + bias (+res) + LayerNorm (+leaky) fused -------------
// BM=64, BN=256, BK=64, 512 threads (8 waves: 2 row-halves x 4 col-quarters),
// double-buffered, 80 KB LDS -> 2 blocks/CU x 8 waves = 16 waves/CU (4/SIMD).
// Used by FFN2 (K=1024).
template<bool ADDRES, bool LEAKY>
__global__ __launch_bounds__(512, 4) void gemm_ln(
    const u16* __restrict__ A, const u16* __restrict__ W,
    const float* __restrict__ bias, const u16* __restrict__ res,
    const float* __restrict__ g, const float* __restrict__ bv,
    u16* __restrict__ outb, float* __restrict__ outf, int K)
{
  constexpr int BM=64, BK=64;
  __shared__ __align__(16) short As[2][BM*BK];     // 2 x 8 KB
  __shared__ __align__(16) short Ws[2][256*BK];    // 2 x 32 KB  (total 80 KB)
  float* S1  = (float*)&As[0][0];                  // [64][4]  (aliased, post-loop)
  float* S2  = S1 + 64*4;                          // [64][4]
  float* MU  = S2 + 64*4;                          // [64]
  float* RSD = MU + 64;                            // [64]
  const int tid = threadIdx.x, lane = tid&63, wid = tid>>6;   // wid 0..7
  const int wm = wid>>2, wn = wid&3;   // wm: 32-row half, wn: 64-col quarter
  const int m0 = blockIdx.x*BM;
  const short* Ag = (const short*)A + (size_t)m0*K;
  const short* Wg = (const short*)W;
  f32x4 acc[2][4] = {};

  auto STAGE = [&](int k0, int buf){   // 5 global_load_lds per thread (1 A + 4 W)
    {
      int c = tid;                     // 0..511
      int row = c>>3;
      int col = (c&7) ^ (row&7);
      gload_lds16(Ag + (size_t)row*K + k0 + col*8, &As[buf][(size_t)c*8]);
    }
    #pragma unroll
    for (int jj=0;jj<4;++jj){
      int c = jj*512 + tid;            // 0..2047
      int row = c>>3;
      int col = (c&7) ^ (row&7);
      gload_lds16(Wg + (size_t)row*K + k0 + col*8, &Ws[buf][(size_t)c*8]);
    }
  };
  auto COMPUTE = [&](int cur){
    #pragma unroll
    for (int kk=0;kk<BK;kk+=32){
      short8 af[2], bfr[4];
      int kc = (kk>>3) + (lane>>4);
      #pragma unroll
      for (int ms=0;ms<2;++ms){
        int r = wm*32 + ms*16 + (lane&15);
        af[ms] = *(const short8*)&As[cur][r*BK + ((kc ^ (r&7))<<3)];
      }
      #pragma unroll
      for (int ns=0;ns<4;++ns){
        int r = wn*64 + ns*16 + (lane&15);
        bfr[ns] = *(const short8*)&Ws[cur][r*BK + ((kc ^ (r&7))<<3)];
      }
      #pragma unroll
      for (int ms=0;ms<2;++ms)
        #pragma unroll
        for (int ns=0;ns<4;++ns)
          acc[ms][ns] = __builtin_amdgcn_mfma_f32_16x16x32_bf16(af[ms], bfr[ns], acc[ms][ns], 0, 0, 0);
    }
  };

  const int NT = K/BK;              // 16 (FFN2)
  STAGE(0, 0); STAGE(BK, 1);
  WAIT_VMCNT(5);                    // t0 complete; t1's 5 stay in flight
  block_sync();
  for (int t=0;t<NT;++t){
    const int cur = t&1;
    __builtin_amdgcn_s_setprio(1);
    COMPUTE(cur);
    __builtin_amdgcn_s_setprio(0);
    block_sync();                   // all waves done reading buf cur
    if (t+2 < NT) STAGE((t+2)*BK, cur);
    if (t+1 < NT){
      if (t+2 < NT) { WAIT_VMCNT(5); }   // complete t+1, keep t+2 in flight
      else          { WAIT_VMCNT(0); }   // tail
      block_sync();
    }
  }
  // bias + residual in place
  #pragma unroll
  for (int ns=0;ns<4;++ns){
    int col = wn*64 + ns*16 + (lane&15);
    float bc = bias[col];
    #pragma unroll
    for (int ms=0;ms<2;++ms){
      int rl = wm*32 + ms*16 + ((lane>>4)<<2);
      #pragma unroll
      for (int i=0;i<4;++i){
        float v = acc[ms][ns][i] + bc;
        if (ADDRES) v += bf2f(res[(size_t)(m0+rl+i)*256 + col]);
        acc[ms][ns][i] = v;
      }
    }
  }
  // per-row partial sums over this wave's 64 cols -> LDS (aliased on As)
  #pragma unroll
  for (int ms=0;ms<2;++ms)
    #pragma unroll
    for (int i=0;i<4;++i){
      float p1 = acc[ms][0][i]+acc[ms][1][i]+acc[ms][2][i]+acc[ms][3][i];
      float p2 = acc[ms][0][i]*acc[ms][0][i] + acc[ms][1][i]*acc[ms][1][i]
               + acc[ms][2][i]*acc[ms][2][i] + acc[ms][3][i]*acc[ms][3][i];
      #pragma unroll
      for (int o=1;o<16;o<<=1){ p1 += __shfl_xor(p1,o,64); p2 += __shfl_xor(p2,o,64); }
      if ((lane&15)==0){
        int rl = wm*32 + ms*16 + ((lane>>4)<<2) + i;
        S1[rl*4 + wn] = p1; S2[rl*4 + wn] = p2;
      }
    }
  __syncthreads();
  if (tid < 64){
    float s1 = S1[tid*4+0]+S1[tid*4+1]+S1[tid*4+2]+S1[tid*4+3];
    float s2 = S2[tid*4+0]+S2[tid*4+1]+S2[tid*4+2]+S2[tid*4+3];
    float mean = s1*(1.f/256.f);
    float var = fmaxf(s2*(1.f/256.f) - mean*mean, 0.f);
    MU[tid] = mean; RSD[tid] = 1.f/sqrtf(var + 1e-5f);
  }
  __syncthreads();
  // LN -> LDS restage (tile is CONTIGUOUS 32KB in global) -> coalesced stores
  constexpr int OP = 268;
  u16* O = (u16*)&Ws[0][0];         // 64*268*2 = 34304 B, fits in Ws
  #pragma unroll
  for (int ns=0;ns<4;++ns){
    int col = wn*64 + ns*16 + (lane&15);
    float gg = g[col], bb = bv[col];
    #pragma unroll
    for (int ms=0;ms<2;++ms){
      int rl = wm*32 + ms*16 + ((lane>>4)<<2);
      #pragma unroll
      for (int i=0;i<4;++i){
        float y = (acc[ms][ns][i] - MU[rl+i])*RSD[rl+i]*gg + bb;
        if (LEAKY) y = y>0.f ? y : 0.01f*y;
        O[(rl+i)*OP + col] = f2bf(y);
        if (outf) outf[(size_t)(m0+rl+i)*256 + col] = y;
      }
    }
  }
  __syncthreads();
  u16* ob = outb + (size_t)m0*256;
  const int rr = tid>>5;            // 32 threads/row, 16 rows/pass
  const int cc = (tid&31)<<3;       // 8 u16 = 16 B per thread
  #pragma unroll
  for (int p=0;p<4;++p){
    int r = p*16 + rr;
    *reinterpret_cast<short8*>(ob + ((size_t)r<<8) + cc) =
        *reinterpret_cast<const short8*>(&O[r*OP + cc]);
  }
}

// -------- fused ring attention + WO GEMM + LN + leaky + SKV GEMM + star scores --------
// R13 vs R12: phase 2 (WO GEMM) drops LDS staging entirely. WO is 128KB and L2-hot;
// its B-fragment pattern (16 lanes x 16 consecutive rows, 4 quarter-waves covering one
// 64B line per row) is fully L2-efficient loaded DIRECTLY to registers with a 2-deep
// named-buffer pipeline (compiler-placed waits; correct by construction). This removes
// all 16 phase-2 barriers + 8 waits (each barrier idled half the CU at 2 blocks/CU).
// STAGE_SKV(0) now issues at KERNEL START and flies across phases 1-3. The LN-stats
// barrier transitively orders phase-2 Afull reads vs phase-3 Afull writes, so no
// replacement barrier is needed. Total barriers ~37 -> ~21.
__global__ __launch_bounds__(512, 4) void attn_ln(
    const u16* __restrict__ qkv, const float* __restrict__ akav,
    const u16* __restrict__ W, const float* __restrict__ bo,
    const float* __restrict__ g, const float* __restrict__ bv,
    const u16* __restrict__ Wskv, const float* __restrict__ bskv,
    const float* __restrict__ sq, float* __restrict__ sbuf,
    u16* __restrict__ svb, u16* __restrict__ outb, float* __restrict__ outf)
{
  constexpr int NT=8;               // 8 K-steps of 32 (WO GEMM)
  __shared__ __align__(16) char LB[68096];
  short* Afull = (short*)LB;                 // [64][256] u16 swizzled, 32 KB
  short* Ws2   = (short*)(LB + 32768);       // [512][32] u16 (WSKV chunk), 32 KB
  float* S1  = (float*)(LB + 65536);         // [64][4]
  float* S2  = S1 + 256;                     // [64][4]
  float* MU  = S2 + 256;                     // [64]
  float* RSD = MU + 64;                      // [64]
  const int tid = threadIdx.x, lane = tid&63, wid = tid>>6;
  const int wm = wid>>2, wn = wid&3;         // WO GEMM: 2 row-halves x 4 col-quarters
  const int m0 = blockIdx.x*64;
  const short* Wg = (const short*)W;

  auto STAGE_SKV = [&](int t){           // 4 global_load_lds per thread (WSKV chunk)
    #pragma unroll
    for (int jj=0;jj<4;++jj){            // [512 rows][4 granules], 32 KB
      int c = jj*512 + tid;
      int row = c>>2;
      int col = (c&3) ^ (row&3);
      gload_lds16((const short*)Wskv + (size_t)row*256 + t*32 + col*8, Ws2 + (size_t)c*8);
    }
  };

  // ---- issue WSKV chunk 0 at kernel start: flies across phases 1-3 (~30us) ----
  STAGE_SKV(0);
  __builtin_amdgcn_sched_barrier(0);

  // ---- phase 1: ring attention, 2 tokens/wave-pass, 8 ch/lane, 16B loads ----
  const int bblk = m0 >> 12;        // batch is uniform across the block (64-token tiles)
  const int j8 = lane & 31;         // channel-octet index (8 ch per lane)
  float ak[8], av[8];
  {
    const float* pa = akav + (size_t)bblk*H_ + j8*8;
    const float* pv = akav + 2048 + (size_t)bblk*H_ + j8*8;
    float4 a0 = *(const float4*)pa, a1 = *(const float4*)(pa+4);
    float4 v0 = *(const float4*)pv, v1 = *(const float4*)(pv+4);
    ak[0]=a0.x; ak[1]=a0.y; ak[2]=a0.z; ak[3]=a0.w;
    ak[4]=a1.x; ak[5]=a1.y; ak[6]=a1.z; ak[7]=a1.w;
    av[0]=v0.x; av[1]=v0.y; av[2]=v0.z; av[3]=v0.w;
    av[4]=v1.x; av[5]=v1.y; av[6]=v1.z; av[7]=v1.w;
  }
  // buffer layout: [0]=q [1]=kc [2]=vc [3]=kp [4]=vp [5]=kn [6]=vn
  auto LOADP = [&](int pp, short8* v){
    const int rl = wid*8 + pp*2 + (lane>>5);
    const size_t tok = (size_t)(m0 + rl);
    const int l = (int)(tok & (L_-1));
    v[0] = *(const short8*)(qkv + tok*768 + j8*8);
    v[1] = *(const short8*)(qkv + tok*768 + 256 + j8*8);
    v[2] = *(const short8*)(qkv + tok*768 + 512 + j8*8);
    const short8 z = {0,0,0,0,0,0,0,0};
    if (l>0){
      v[3] = *(const short8*)(qkv + (tok-1)*768 + 256 + j8*8);
      v[4] = *(const short8*)(qkv + (tok-1)*768 + 512 + j8*8);
    } else { v[3]=z; v[4]=z; }
    if (l<L_-1){
      v[5] = *(const short8*)(qkv + (tok+1)*768 + 256 + j8*8);
      v[6] = *(const short8*)(qkv + (tok+1)*768 + 512 + j8*8);
    } else { v[5]=z; v[6]=z; }
  };
  auto PASS = [&](int pp, const short8* v){
    const int rl = wid*8 + pp*2 + (lane>>5);
    float dp=0.f, dc=0.f, dn=0.f, da=0.f;
    #pragma unroll
    for (int c=0;c<8;++c){
      float qc = bf2f((u16)v[0][c]);
      dp += qc*bf2f((u16)v[3][c]);
      dc += qc*bf2f((u16)v[1][c]);
      dn += qc*bf2f((u16)v[5][c]);
      da += qc*ak[c];
    }
    #pragma unroll
    for (int o=1;o<8;o<<=1){           // reduce within the 8-lane head group
      dp += __shfl_xor(dp,o,64); dc += __shfl_xor(dc,o,64);
      dn += __shfl_xor(dn,o,64); da += __shfl_xor(da,o,64);
    }
    dp *= 0.125f; dc *= 0.125f; dn *= 0.125f; da *= 0.125f;
    float m = fmaxf(fmaxf(dp,dc), fmaxf(dn,da));
    float e0 = __expf(dp-m), e1 = __expf(dc-m), e2 = __expf(dn-m), e3 = __expf(da-m);
    float rd = 1.f/(e0+e1+e2+e3);
    short8 ov;
    #pragma unroll
    for (int c=0;c<8;++c)
      ov[c] = (short)f2bf((e0*bf2f((u16)v[4][c]) + e1*bf2f((u16)v[2][c])
                         + e2*bf2f((u16)v[6][c]) + e3*av[c])*rd);
    int s = (j8 & ~7) | ((j8&7) ^ (rl&7));
    *(short8*)&Afull[rl*256 + s*8] = ov;
  };
  {
    short8 bA[7], bB[7];
    LOADP(0, bA);
    LOADP(1, bB);
    PASS(0, bA);
    LOADP(2, bA);
    PASS(1, bB);
    LOADP(3, bB);
    PASS(2, bA);
    PASS(3, bB);
  }
  WAIT_LGKM0();                     // Afull ds_writes complete
  block_sync();

  // ---- phase 2: WO GEMM, K=256 in 8 steps; B-frags direct global->reg, 2-deep ----
  f32x4 acc[2][4] = {};
  {
    auto LDFRAG = [&](int t, short8* b){   // 4 x 16B loads; 16 rows share 64B lines
      #pragma unroll
      for (int ns=0;ns<4;++ns){
        int r2 = wn*64 + ns*16 + (lane&15);
        b[ns] = *(const short8*)(Wg + (size_t)r2*256 + t*32 + (lane>>4)*8);
      }
    };
    auto MM = [&](int t, const short8* b){
      short8 af[2];
      #pragma unroll
      for (int ms=0;ms<2;++ms){
        int r = wm*32 + ms*16 + (lane&15);
        int gk = t*4 + (lane>>4);
        int s = (gk & ~7) | ((gk&7) ^ (r&7));
        af[ms] = *(const short8*)&Afull[r*256 + s*8];
      }
      #pragma unroll
      for (int ms=0;ms<2;++ms)
        #pragma unroll
        for (int ns=0;ns<4;++ns)
          acc[ms][ns] = __builtin_amdgcn_mfma_f32_16x16x32_bf16(af[ms], b[ns], acc[ms][ns], 0, 0, 0);
    };
    short8 fA[4], fB[4];
    LDFRAG(0, fA); LDFRAG(1, fB);
    MM(0, fA); LDFRAG(2, fA);
    MM(1, fB); LDFRAG(3, fB);
    MM(2, fA); LDFRAG(4, fA);
    MM(3, fB); LDFRAG(5, fB);
    MM(4, fA); LDFRAG(6, fA);
    MM(5, fB); LDFRAG(7, fB);
    MM(6, fA);
    MM(7, fB);
  }
  // NO barrier here: the LN-stats barrier below transitively orders all waves'
  // phase-2 Afull reads before any wave's phase-3 Afull writes.

  // ---- phase 3: bias + LN + leaky -> Afull (swizzled) -> coalesced NB store ----
  #pragma unroll
  for (int ns=0;ns<4;++ns){
    int col = wn*64 + ns*16 + (lane&15);
    float bc = bo[col];
    #pragma unroll
    for (int ms=0;ms<2;++ms)
      #pragma unroll
      for (int i=0;i<4;++i)
        acc[ms][ns][i] += bc;
  }
  #pragma unroll
  for (int ms=0;ms<2;++ms)
    #pragma unroll
    for (int i=0;i<4;++i){
      float p1 = acc[ms][0][i]+acc[ms][1][i]+acc[ms][2][i]+acc[ms][3][i];
      float p2 = acc[ms][0][i]*acc[ms][0][i] + acc[ms][1][i]*acc[ms][1][i]
               + acc[ms][2][i]*acc[ms][2][i] + acc[ms][3][i]*acc[ms][3][i];
      #pragma unroll
      for (int o=1;o<16;o<<=1){ p1 += __shfl_xor(p1,o,64); p2 += __shfl_xor(p2,o,64); }
      if ((lane&15)==0){
        int rl = wm*32 + ms*16 + ((lane>>4)<<2) + i;
        S1[rl*4 + wn] = p1; S2[rl*4 + wn] = p2;
      }
    }
  WAIT_LGKM0(); block_sync();
  if (tid < 64){
    float s1 = S1[tid*4+0]+S1[tid*4+1]+S1[tid*4+2]+S1[tid*4+3];
    float s2 = S2[tid*4+0]+S2[tid*4+1]+S2[tid*4+2]+S2[tid*4+3];
    float mean = s1*(1.f/256.f);
    float var = fmaxf(s2*(1.f/256.f) - mean*mean, 0.f);
    MU[tid] = mean; RSD[tid] = 1.f/sqrtf(var + 1e-5f);
  }
  WAIT_LGKM0(); block_sync();
  #pragma unroll
  for (int ns=0;ns<4;++ns){
    int col = wn*64 + ns*16 + (lane&15);
    float gg = g[col], bb = bv[col];
    #pragma unroll
    for (int ms=0;ms<2;++ms){
      int rl = wm*32 + ms*16 + ((lane>>4)<<2);
      #pragma unroll
      for (int i=0;i<4;++i){
        float y = (acc[ms][ns][i] - MU[rl+i])*RSD[rl+i]*gg + bb;
        y = y>0.f ? y : 0.01f*y;
        int row = rl+i, cg = col>>3;
        int s = (cg & ~7) | ((cg&7) ^ (row&7));
        Afull[row*256 + s*8 + (col&7)] = f2bf(y);
        if (outf) outf[(size_t)(m0+row)*256 + col] = y;
      }
    }
  }
  WAIT_LGKM0(); block_sync();
  const int rr = tid>>5, cg8 = tid&31;   // 32 threads/row, 16B granule each
  {
    u16* ob = outb + (size_t)m0*256;
    #pragma unroll
    for (int p=0;p<4;++p){
      int r = p*16 + rr;
      int s = (cg8 & ~7) | ((cg8&7) ^ (r&7));
      *reinterpret_cast<short8*>(ob + ((size_t)r<<8) + cg8*8) =
          *reinterpret_cast<const short8*>(&Afull[r*256 + s*8]);
    }
  }

  // ---- phase 4: SKV GEMM (A = resident Afull, WSKV reg-stage pipelined via Ws2) ----
  // 8 N-bands of 64 cols (band = wid); bands 0-3 = K-half (scores only, never stored),
  // bands 4-7 = V-half -> SVB.
  f32x4 acc2[4][4] = {};
  for (int t=0;t<8;++t){
    WAIT_VMCNT(0);                       // chunk t landed (also drains NB stores, 1st iter)
    block_sync();
    short8 af[4], bf4[4];
    #pragma unroll
    for (int ms=0;ms<4;++ms){
      int r = ms*16 + (lane&15);
      int gk = t*4 + (lane>>4);
      int s = (gk & ~7) | ((gk&7) ^ (r&7));
      af[ms] = *(const short8*)&Afull[r*256 + s*8];
    }
    #pragma unroll
    for (int ns=0;ns<4;++ns){
      int n = wid*64 + ns*16 + (lane&15);
      int sl = (lane>>4) ^ (n&3);
      bf4[ns] = *(const short8*)&Ws2[n*32 + sl*8];
    }
    WAIT_LGKM0();                        // chunk t safely in registers
    block_sync();                        // all waves done reading Ws2
    if (t+1 < 8) STAGE_SKV(t+1);         // overwrite Ws2; latency hides under MFMA
    __builtin_amdgcn_s_setprio(1);
    #pragma unroll
    for (int ms=0;ms<4;++ms)
      #pragma unroll
      for (int ns=0;ns<4;++ns)
        acc2[ms][ns] = __builtin_amdgcn_mfma_f32_16x16x32_bf16(af[ms], bf4[ns], acc2[ms][ns], 0, 0, 0);
    __builtin_amdgcn_s_setprio(0);
  }
  // epilogue: scores (bands 0-3, f32 pre-round) / V-half restage (bands 4-7)
  u16* O2 = (u16*)LB;                    // [64][256] u16 over dead Afull (reads all done)
  if (wid < 4){
    float sqv[4], bcv[4];
    #pragma unroll
    for (int ns=0;ns<4;++ns){
      int n = wid*64 + ns*16 + (lane&15);
      sqv[ns] = sq[bblk*H_ + n];
      bcv[ns] = bskv[n];
    }
    #pragma unroll
    for (int ms=0;ms<4;++ms)
      #pragma unroll
      for (int i=0;i<4;++i){
        float p = (acc2[ms][0][i]+bcv[0])*sqv[0] + (acc2[ms][1][i]+bcv[1])*sqv[1]
                + (acc2[ms][2][i]+bcv[2])*sqv[2] + (acc2[ms][3][i]+bcv[3])*sqv[3];
        #pragma unroll
        for (int o=1;o<16;o<<=1) p += __shfl_xor(p,o,64);
        if ((lane&15)==0){
          int rl = ms*16 + ((lane>>4)<<2) + i;
          int l = (m0 + rl) & (L_-1);
          sbuf[(size_t)(bblk*4 + wid)*(L_+1) + 1 + l] = p*0.125f;
        }
      }
  } else {
    #pragma unroll
    for (int ns=0;ns<4;++ns){
      int n = wid*64 + ns*16 + (lane&15);
      float bc = bskv[n];
      #pragma unroll
      for (int ms=0;ms<4;++ms){
        int rb = ms*16 + ((lane>>4)<<2);
        #pragma unroll
        for (int i=0;i<4;++i)
          O2[(rb+i)*256 + (n-256)] = f2bf(acc2[ms][ns][i] + bc);
      }
    }
  }
  WAIT_LGKM0(); block_sync();
  // coalesced V store: 64 rows x 512 B
  u16* vb = svb + (size_t)m0*256;
  #pragma unroll
  for (int p=0;p<4;++p){
    int r = p*16 + rr;
    *reinterpret_cast<short8*>(vb + ((size_t)r<<8) + cg8*8) =
        *reinterpret_cast<const short8*>(&O2[r*256 + cg8*8]);
  }
}

// ---------------- star attention: per-row max + 1/sum (+ j=0 self-score) ----------------
__global__ __launch_bounds__(256) void star_maxsum(
    float* __restrict__ s, const float* __restrict__ sq,
    const float* __restrict__ sk0, float* __restrict__ sms)
{
  const int bh = blockIdx.x;        // b*4 + h
  const int b = bh>>2, h = bh&3;
  float* row = s + (size_t)bh*(L_+1);
  __shared__ float red[256];
  const int tid = threadIdx.x;
  // j=0 relay self-score
  float p0 = (tid < 64) ? sq[b*H_ + h*64 + tid]*sk0[b*H_ + h*64 + tid] : 0.f;
  red[tid] = p0; __syncthreads();
  for (int st=128; st>0; st>>=1){ if (tid<st) red[tid] += red[tid+st]; __syncthreads(); }
  const float s0 = red[0]*0.125f;
  if (tid==0) row[0] = s0;
  __syncthreads();
  float m = s0;
  for (int j=1+tid; j<=L_; j+=256) m = fmaxf(m, row[j]);
  red[tid] = m; __syncthreads();
  for (int st=128; st>0; st>>=1){ if (tid<st) red[tid] = fmaxf(red[tid], red[tid+st]); __syncthreads(); }
  m = red[0]; __syncthreads();
  float sum = (tid==0) ? expf(s0-m) : 0.f;
  for (int j=1+tid; j<=L_; j+=256) sum += expf(row[j]-m);
  red[tid] = sum; __syncthreads();
  for (int st=128; st>0; st>>=1){ if (tid<st) red[tid] += red[tid+st]; __syncthreads(); }
  if (tid==0){ sms[bh*2] = m; sms[bh*2+1] = 1.f/red[0]; }
}

// partial over 64-token segments, all 4 heads per block: grid = B_*64
// applies exp(s-m)*rs inline (raw scores in a); V from the dedicated SVB buffer
__global__ __launch_bounds__(256) void star_satt_part(
    const float* __restrict__ a, const float* __restrict__ sms,
    const u16* __restrict__ svb, float* __restrict__ part)
{
  const int blk = blockIdx.x;
  const int b = blk >> 6, seg = blk & 63;
  const int tid = threadIdx.x, q4 = tid & 63, sub = tid >> 6;
  const int h = q4 >> 4;
  const float* arow = a + (size_t)(b*4 + h)*(L_+1) + 1;
  const float m = sms[(b*4+h)*2], rs = sms[(b*4+h)*2+1];
  float a0=0.f,a1=0.f,a2=0.f,a3=0.f;
  const int j0 = seg*64 + sub*16;
  #pragma unroll 4
  for (int jj=j0; jj<j0+16; ++jj){
    u16x4 v = *(const u16x4*)(svb + ((size_t)b*L_ + jj)*256 + q4*4);
    float al = expf(arow[jj]-m)*rs;
    a0 += al*bf2f(v.x); a1 += al*bf2f(v.y); a2 += al*bf2f(v.z); a3 += al*bf2f(v.w);
  }
  __shared__ float red[4][256];
  red[sub][q4*4+0]=a0; red[sub][q4*4+1]=a1; red[sub][q4*4+2]=a2; red[sub][q4*4+3]=a3;
  __syncthreads();
  if (sub==0){
    #pragma unroll
    for (int c=0;c<4;++c){
      int ch = q4*4+c;
      part[(size_t)blk*256 + ch] = red[0][ch]+red[1][ch]+red[2][ch]+red[3][ch];
    }
  }
}

// ---------------- relay weight transpose pack ----------------
__global__ __launch_bounds__(256) void pack_wT(
    const float* __restrict__ w0, const float* __restrict__ w1,
    const float* __restrict__ w2, const float* __restrict__ w3,
    const float* __restrict__ w4, const float* __restrict__ w5,
    float* __restrict__ T)
{
  __shared__ float tile[32][33];
  const int blk = blockIdx.x;           // NL*6*64
  const int t = blk & 63, m = blk >> 6;
  const int l = m / 6, w = m % 6;
  const float* srcs[6] = {w0, w1, w2, w3, w4, w5};
  const float* src = srcs[w] + (size_t)l*65536;
  const int r0 = (t>>3)*32, c0 = (t&7)*32;
  const int rr = threadIdx.x >> 5, cc = threadIdx.x & 31;   // 8 rows/pass
  #pragma unroll
  for (int p=0;p<4;++p)
    tile[rr + p*8][cc] = src[(size_t)(r0 + rr + p*8)*256 + c0 + cc];
  __syncthreads();
  float* dst = T + (size_t)m*65536;
  #pragma unroll
  for (int p=0;p<4;++p)
    dst[(size_t)(c0 + rr + p*8)*256 + r0 + cc] = tile[cc][rr + p*8];
}

// ---------------- tiny relay projections (transposed f32 weights, coalesced) ----------------
struct TPB { const float* b; float* out; };
struct TPB5 { TPB p[5]; };
__global__ __launch_bounds__(256) void relay_projs(
    const float* __restrict__ relay, const float* __restrict__ TW, TPB5 tp)
{
  const int b = blockIdx.x, w = blockIdx.y, n = threadIdx.x;
  __shared__ float rs[H_];
  rs[n] = relay[b*H_ + n];
  __syncthreads();
  const float* wt = TW + (size_t)w*65536;
  float s = tp.p[w].b[n];
  #pragma unroll 8
  for (int c=0;c<H_;++c) s += rs[c]*wt[(size_t)c*256 + n];
  tp.p[w].out[b*H_+n] = s;
}

// ---------------- relay tail: satt combine + star W_o matvec (transposed) + leaky ----------------
__global__ __launch_bounds__(256) void relay_tail_k(
    const float* __restrict__ part, const float* __restrict__ a,
    const float* __restrict__ sms, const float* __restrict__ sv0,
    const float* __restrict__ TW, const float* __restrict__ bo,
    float* __restrict__ relay, float* __restrict__ outr)
{
  const int b = blockIdx.x, n = threadIdx.x;
  __shared__ float rs[H_];
  const int h = n >> 6;
  const float m = sms[(b*4+h)*2], rsum = sms[(b*4+h)*2+1];
  float a0 = expf(a[(size_t)(b*4+h)*(L_+1)] - m)*rsum;
  float s = a0 * sv0[b*H_ + n];
  #pragma unroll 8
  for (int g2=0; g2<64; ++g2) s += part[((size_t)b*64+g2)*256 + n];
  rs[n] = s;
  __syncthreads();
  const float* wt = TW + (size_t)5*65536;   // star_wo slot
  float v = bo[n];
  #pragma unroll 8
  for (int c=0;c<H_;++c) v += rs[c]*wt[(size_t)c*256 + n];
  v = v>0.f ? v : 0.01f*v;
  relay[b*H_+n] = v;
  if (outr) outr[b*H_+n] = v;
}

// ---------------- setup kernels ----------------
__global__ void f32_to_bf16_k(const float* __restrict__ s, u16* __restrict__ d, int n){
  for (int i = blockIdx.x*blockDim.x + threadIdx.x; i < n; i += gridDim.x*blockDim.x)
    d[i] = f2bf(s[i]);
}
__global__ void pack_wqkv(const float* __restrict__ wq, const float* __restrict__ wk,
                          const float* __restrict__ wv, u16* __restrict__ dst){
  const int n = NL_*768*H_;
  for (int i = blockIdx.x*blockDim.x + threadIdx.x; i < n; i += gridDim.x*blockDim.x){
    int l = i/(768*H_); int rem = i%(768*H_); int r = rem/H_; int c = rem%H_;
    float v = (r<256) ? wq[((size_t)l*H_ + r)*H_ + c]
            : (r<512) ? wk[((size_t)l*H_ + (r-256))*H_ + c]
                      : wv[((size_t)l*H_ + (r-512))*H_ + c];
    dst[i] = f2bf(v);
  }
}
__global__ void pack_wskv(const float* __restrict__ wk, const float* __restrict__ wv, u16* __restrict__ dst){
  const int n = NL_*512*H_;
  for (int i = blockIdx.x*blockDim.x + threadIdx.x; i < n; i += gridDim.x*blockDim.x){
    int l = i/(512*H_); int rem = i%(512*H_); int r = rem/H_; int c = rem%H_;
    float v = (r<256) ? wk[((size_t)l*H_ + r)*H_ + c]
                      : wv[((size_t)l*H_ + (r-256))*H_ + c];
    dst[i] = f2bf(v);
  }
}
__global__ void pack_biases(const float* __restrict__ bq, const float* __restrict__ bk,
                            const float* __restrict__ bv, float* __restrict__ dqkv,
                            const float* __restrict__ sbk, const float* __restrict__ sbv,
                            float* __restrict__ dskv){
  int i = blockIdx.x*blockDim.x + threadIdx.x;
  if (i < NL_*768){
    int l = i/768, r = i%768;
    dqkv[i] = (r<256) ? bq[l*H_+r] : (r<512) ? bk[l*H_+r-256] : bv[l*H_+r-512];
  }
  if (i < NL_*512){
    int l = i/512, r = i%512;
    dskv[i] = (r<256) ? sbk[l*H_+r] : sbv[l*H_+r-256];
  }
}
__global__ void init_nodes(const float* __restrict__ data, const float* __restrict__ pos, u16* __restrict__ nodes){
  const int total = TOK_*H_/4;
  int i = blockIdx.x*blockDim.x + threadIdx.x;
  if (i >= total) return;
  float4 d = ((const float4*)data)[i];
  float4 p = ((const float4*)pos)[i % (L_*H_/4)];
  u16x4 o; o.x=f2bf(d.x+p.x); o.y=f2bf(d.y+p.y); o.z=f2bf(d.z+p.z); o.w=f2bf(d.w+p.w);
  ((u16x4*)nodes)[i] = o;
}
__global__ void relay_partial(const float* __restrict__ data, const float* __restrict__ pos, float* __restrict__ part){
  const int b = blockIdx.x>>3, seg = blockIdx.x&7, hh = threadIdx.x;
  float s = 0.f;
  for (int l = seg*512; l < seg*512+512; ++l)
    s += data[((size_t)b*L_ + l)*H_ + hh] + pos[(size_t)l*H_ + hh];
  part[blockIdx.x*H_ + hh] = s;
}
__global__ void relay_combine(const float* __restrict__ part, float* __restrict__ relay){
  const int b = blockIdx.x, hh = threadIdx.x;
  float s = 0.f;
  for (int g=0; g<8; ++g) s += part[(b*8+g)*H_ + hh];
  relay[b*H_+hh] = s * (1.0f/L_);
}

extern "C" void kernel_launch(void* const* d_in, const int* in_sizes, int n_in,
                              void* d_out, int out_size, void* d_ws, size_t ws_size,
                              hipStream_t stream)
{
  const float* data   = (const float*)d_in[0];
  const float* pos    = (const float*)d_in[2];
  const float* ln_g   = (const float*)d_in[3];
  const float* ln_b   = (const float*)d_in[4];
  const float* ff_w1  = (const float*)d_in[5];
  const float* ff_b1  = (const float*)d_in[6];
  const float* ff_w2  = (const float*)d_in[7];
  const float* ff_b2  = (const float*)d_in[8];
  const float* ff_lng = (const float*)d_in[9];
  const float* ff_lnb = (const float*)d_in[10];
  const float* ring_wq= (const float*)d_in[11]; const float* ring_bq= (const float*)d_in[12];
  const float* ring_wk= (const float*)d_in[13]; const float* ring_bk= (const float*)d_in[14];
  const float* ring_wv= (const float*)d_in[15]; const float* ring_bv= (const float*)d_in[16];
  const float* ring_wo= (const float*)d_in[17]; const float* ring_bo= (const float*)d_in[18];
  const float* star_wq= (const float*)d_in[19]; const float* star_bq= (const float*)d_in[20];
  const float* star_wk= (const float*)d_in[21]; const float* star_bk= (const float*)d_in[22];
  const float* star_wv= (const float*)d_in[23]; const float* star_bv= (const float*)d_in[24];
  const float* star_wo= (const float*)d_in[25]; const float* star_bo= (const float*)d_in[26];

  char* ws = (char*)d_ws;
  size_t off = 0;
  auto alc = [&](size_t n){ size_t cur = off; off = (cur + n + 255) & ~(size_t)255; return (void*)(ws + cur); };
  u16*  W1B   = (u16*)alc((size_t)NL_*DI_*H_*2);
  u16*  W2B   = (u16*)alc((size_t)NL_*H_*DI_*2);
  u16*  WQKVB = (u16*)alc((size_t)NL_*768*H_*2);
  u16*  WOB   = (u16*)alc((size_t)NL_*H_*H_*2);
  u16*  WSKVB = (u16*)alc((size_t)NL_*512*H_*2);
  float* BQKVB= (float*)alc((size_t)NL_*768*4);
  float* BSKVB= (float*)alc((size_t)NL_*512*4);
  float* TWB  = (float*)alc((size_t)NL_*6*H_*H_*4);   // transposed relay weights, 9.4 MB
  u16*  NB    = (u16*)alc((size_t)TOK_*H_*2);
  u16*  HB    = (u16*)alc((size_t)TOK_*H_*2);
  u16*  T1R   = (u16*)alc((size_t)TOK_*DI_*2);   // aliased: T1 | QKV
  u16*  SVB   = (u16*)alc((size_t)TOK_*256*2);   // star V (dedicated: attn_ln writes while reading QKV)
  float* RELAY  = (float*)alc(B_*H_*4);
  float* PART   = (float*)alc(64*H_*4);
  float* AKAV   = (float*)alc(2*B_*H_*4);
  float* SQB    = (float*)alc(B_*H_*4);
  float* SK0B   = (float*)alc(B_*H_*4);
  float* SV0B   = (float*)alc(B_*H_*4);
  float* SBUF   = (float*)alc((size_t)B_*NH_*(L_+1)*4);
  float* SMS    = (float*)alc((size_t)B_*NH_*2*4);
  float* SPART  = (float*)alc((size_t)B_*64*256*4);
  u16* QKVB = T1R;

  // weight conversion / packing (deterministic, every call)
  f32_to_bf16_k<<<2048, 256, 0, stream>>>(ff_w1, W1B, NL_*DI_*H_);
  f32_to_bf16_k<<<2048, 256, 0, stream>>>(ff_w2, W2B, NL_*H_*DI_);
  f32_to_bf16_k<<<1024, 256, 0, stream>>>(ring_wo, WOB, NL_*H_*H_);
  pack_wqkv<<<2048, 256, 0, stream>>>(ring_wq, ring_wk, ring_wv, WQKVB);
  pack_wskv<<<2048, 256, 0, stream>>>(star_wk, star_wv, WSKVB);
  pack_biases<<<18, 256, 0, stream>>>(ring_bq, ring_bk, ring_bv, BQKVB, star_bk, star_bv, BSKVB);
  pack_wT<<<NL_*6*64, 256, 0, stream>>>(ring_wk, ring_wv, star_wq, star_wk, star_wv, star_wo, TWB);

  init_nodes<<<(TOK_*H_/4 + 255)/256, 256, 0, stream>>>(data, pos, NB);
  relay_partial<<<64, 256, 0, stream>>>(data, pos, PART);
  relay_combine<<<B_, 256, 0, stream>>>(PART, RELAY);

  for (int l=0; l<NL_; ++l){
    const float* TWl = TWB + (size_t)l*6*H_*H_;
    // FFN1: relu(NB @ W1^T + b1) -> T1R
    gemm_bt<true,true><<<(DI_/128)*(TOK_/128), 512, 0, stream>>>(
        NB, W1B + (size_t)l*DI_*H_, ff_b1 + l*DI_, T1R, DI_, H_, DI_/128);
    // FFN2 + residual(NB) + LN -> HB
    gemm_ln<true,false><<<TOK_/64, 512, 0, stream>>>(
        T1R, W2B + (size_t)l*H_*DI_, ff_b2 + l*H_, NB,
        ff_lng + l*H_, ff_lnb + l*H_, HB, nullptr, DI_);
    // relay-dependent small projections (relay from previous layer; coalesced TW reads)
    TPB5 tp;
    tp.p[0] = { ring_bk + l*H_, AKAV };
    tp.p[1] = { ring_bv + l*H_, AKAV + 2048 };
    tp.p[2] = { star_bq + l*H_, SQB };
    tp.p[3] = { star_bk + l*H_, SK0B };
    tp.p[4] = { star_bv + l*H_, SV0B };
    relay_projs<<<dim3(B_,5), 256, 0, stream>>>(RELAY, TWl, tp);
    // ring QKV projection
    gemm_bt<false,true><<<(768/128)*(TOK_/128), 512, 0, stream>>>(
        HB, WQKVB + (size_t)l*768*H_, BQKVB + l*768, QKVB, 768, H_, 768/128);
    // fused: ring attention + WO + LN + leaky -> NB; SKV GEMM -> scores + V-half
    attn_ln<<<TOK_/64, 512, 0, stream>>>(
        QKVB, AKAV, WOB + (size_t)l*H_*H_, ring_bo + l*H_,
        ln_g + l*H_, ln_b + l*H_,
        WSKVB + (size_t)l*512*H_, BSKVB + l*512,
        SQB, SBUF, SVB, NB,
        (l==NL_-1) ? (float*)d_out : nullptr);
    // per-row max + 1/sum (+ relay self-score) -> SMS, SBUF[.,0]
    star_maxsum<<<B_*NH_, 256, 0, stream>>>(SBUF, SQB, SK0B, SMS);
    star_satt_part<<<B_*64, 256, 0, stream>>>(SBUF, SMS, SVB, SPART);
    // satt combine + star W_o matvec + leaky -> RELAY (+f32 d_out at last layer)
    relay_tail_k<<<B_, 256, 0, stream>>>(SPART, SBUF, SMS, SV0B, TWl,
        star_bo + l*H_, RELAY,
        (l==NL_-1) ? ((float*)d_out + (size_t)TOK_*H_) : nullptr);
  }
}

// Round 14
// 1011.574 us; speedup vs baseline: 1.0712x; 1.0712x over previous
//
#include <hip/hip_runtime.h>
#include <hip/hip_bf16.h>

#define B_ 8
#define L_ 4096
#define H_ 256
#define NH_ 4
#define DI_ 1024
#define NL_ 6
#define TOK_ (B_*L_)

typedef unsigned short u16;
typedef __attribute__((ext_vector_type(8))) short short8;
typedef __attribute__((ext_vector_type(4))) float f32x4;

struct __align__(8) u16x4 { u16 x,y,z,w; };

__device__ __forceinline__ float bf2f(u16 u){
  union { unsigned u; float f; } c; c.u = ((unsigned)u)<<16; return c.f;
}
__device__ __forceinline__ u16 f2bf(float f){
  union { float f; unsigned u; } c; c.f = f;
  unsigned r = c.u + 0x7FFF + ((c.u>>16)&1);
  return (u16)(r>>16);
}
__device__ __forceinline__ void gload_lds16(const short* g, short* l){
  __builtin_amdgcn_global_load_lds(
      (const __attribute__((address_space(1))) void*)g,
      (__attribute__((address_space(3))) void*)l, 16, 0, 0);
}
// raw block barrier WITHOUT the vmcnt(0) drain __syncthreads would emit.
__device__ __forceinline__ void block_sync(){
  asm volatile("" ::: "memory");
  __builtin_amdgcn_s_barrier();
  __builtin_amdgcn_sched_barrier(0);
}
#define WAIT_VMCNT(N) asm volatile("s_waitcnt vmcnt(" #N ")" ::: "memory")
#define WAIT_LGKM0()  asm volatile("s_waitcnt lgkmcnt(0)" ::: "memory")

// ---------------- bf16 MFMA GEMM: out[M,N] = A[M,K] @ W[N,K]^T + bias ----------------
// BM=BN=128, BK=64, 512 threads (8 waves of 32x64 out), double-buffered LDS,
// counted-vmcnt depth-2. LDS 64KB -> 2 blocks/CU x 8 waves = 16 waves/CU (4/SIMD).
// 1-D grid nbn*256; XCD decode: each XCD owns a contiguous 32-M-tile range.
template<bool RELU, bool OBF16>
__global__ __launch_bounds__(512, 4) void gemm_bt(
    const u16* __restrict__ A, const u16* __restrict__ W,
    const float* __restrict__ bias, void* __restrict__ out, int N, int K, int nbn)
{
  constexpr int BM=128, BK=64;
  __shared__ __align__(16) short As[2][BM*BK];   // 2 x 16 KB
  __shared__ __align__(16) short Ws[2][BM*BK];   // 2 x 16 KB
  const int tid = threadIdx.x, lane = tid&63, wid = tid>>6;   // wid 0..7
  const int wm = wid>>1, wn = wid&1;   // wm: 32-row band, wn: 64-col half
  const int id = blockIdx.x;
  const int xcd = id & 7, j = id >> 3;
  const int bm = xcd*32 + j / nbn;
  const int bn = j % nbn;
  const short* Ag = (const short*)A + (size_t)bm*BM*K;
  const short* Wg = (const short*)W + (size_t)bn*BM*K;
  f32x4 acc[2][4] = {};

  auto STAGE = [&](int k0, int buf){   // 4 global_load_lds per thread (2 A + 2 W)
    #pragma unroll
    for (int jj=0;jj<2;++jj){
      int c = jj*512 + tid;            // 16B-chunk index 0..1023
      int row = c>>3;
      int col = (c&7) ^ (row&7);
      const size_t src = (size_t)row*K + k0 + col*8;
      gload_lds16(Ag + src, &As[buf][(size_t)c*8]);
      gload_lds16(Wg + src, &Ws[buf][(size_t)c*8]);
    }
  };
  auto COMPUTE = [&](int cur){
    #pragma unroll
    for (int kk=0;kk<BK;kk+=32){
      short8 af[2], bfr[4];
      int kc = (kk>>3) + (lane>>4);
      #pragma unroll
      for (int ms=0;ms<2;++ms){
        int r = wm*32 + ms*16 + (lane&15);
        af[ms] = *(const short8*)&As[cur][r*BK + ((kc ^ (r&7))<<3)];
      }
      #pragma unroll
      for (int ns=0;ns<4;++ns){
        int r = wn*64 + ns*16 + (lane&15);
        bfr[ns] = *(const short8*)&Ws[cur][r*BK + ((kc ^ (r&7))<<3)];
      }
      #pragma unroll
      for (int ms=0;ms<2;++ms)
        #pragma unroll
        for (int ns=0;ns<4;++ns)
          acc[ms][ns] = __builtin_amdgcn_mfma_f32_16x16x32_bf16(af[ms], bfr[ns], acc[ms][ns], 0, 0, 0);
    }
  };

  const int NT = K/BK;              // >= 2 for all call sites (K=256)
  STAGE(0, 0); STAGE(BK, 1);
  WAIT_VMCNT(4);                    // t0 complete; t1's 4 stay in flight
  block_sync();
  for (int t=0;t<NT;++t){
    const int cur = t&1;
    __builtin_amdgcn_s_setprio(1);
    COMPUTE(cur);
    __builtin_amdgcn_s_setprio(0);
    block_sync();                   // all waves done reading buf cur
    if (t+2 < NT) STAGE((t+2)*BK, cur);
    if (t+1 < NT){
      if (t+2 < NT) { WAIT_VMCNT(4); }   // complete t+1, keep t+2 in flight
      else          { WAIT_VMCNT(0); }   // tail
      block_sync();
    }
  }
  // ---- epilogue: bias (+relu) -> LDS restage -> coalesced 16B/lane stores ----
  if (OBF16){
    constexpr int OP = 136;         // padded LDS row stride (u16) to break bank alias
    u16* O = (u16*)&As[0][0];       // 128*136*2 = 34816 B over dead As(+head of Ws)
    #pragma unroll
    for (int ns=0;ns<4;++ns){
      int lc = wn*64 + ns*16 + (lane&15);
      float bc = bias[bn*BM + lc];
      #pragma unroll
      for (int ms=0;ms<2;++ms){
        int rbase = wm*32 + ms*16 + ((lane>>4)<<2);
        #pragma unroll
        for (int i=0;i<4;++i){
          float v = acc[ms][ns][i] + bc;
          if (RELU) v = fmaxf(v, 0.f);
          O[(rbase+i)*OP + lc] = f2bf(v);
        }
      }
    }
    block_sync();
    u16* ob = (u16*)out + (size_t)bm*BM*N + bn*BM;
    const int rr = tid>>4;          // 16 threads/row, 32 rows/pass
    const int cc = (tid&15)<<3;     // 8 u16 = 16 B per thread
    #pragma unroll
    for (int p=0;p<4;++p){
      int r = p*32 + rr;
      *reinterpret_cast<short8*>(ob + (size_t)r*N + cc) =
          *reinterpret_cast<const short8*>(&O[r*OP + cc]);
    }
  } else {
    const int r0 = bm*BM + wm*32;
    const int c0 = bn*BM + wn*64;
    #pragma unroll
    for (int ns=0;ns<4;++ns){
      int col = c0 + ns*16 + (lane&15);
      float bc = bias[col];
      #pragma unroll
      for (int ms=0;ms<2;++ms){
        int rbase = r0 + ms*16 + ((lane>>4)<<2);
        #pragma unroll
        for (int i=0;i<4;++i){
          float v = acc[ms][ns][i] + bc;
          if (RELU) v = fmaxf(v, 0.f);
          ((float*)out)[(size_t)(rbase+i)*N + col] = v;
        }
      }
    }
  }
}

// ------------- GEMM (N=256 full) + bias (+res) + LayerNorm (+leaky) fused -------------
// BM=64, BN=256, BK=64, 512 threads (8 waves: 2 row-halves x 4 col-quarters),
// double-buffered, 80 KB LDS -> 2 blocks/CU x 8 waves = 16 waves/CU (4/SIMD).
// Used by FFN2 (K=1024).
template<bool ADDRES, bool LEAKY>
__global__ __launch_bounds__(512, 4) void gemm_ln(
    const u16* __restrict__ A, const u16* __restrict__ W,
    const float* __restrict__ bias, const u16* __restrict__ res,
    const float* __restrict__ g, const float* __restrict__ bv,
    u16* __restrict__ outb, float* __restrict__ outf, int K)
{
  constexpr int BM=64, BK=64;
  __shared__ __align__(16) short As[2][BM*BK];     // 2 x 8 KB
  __shared__ __align__(16) short Ws[2][256*BK];    // 2 x 32 KB  (total 80 KB)
  float* S1  = (float*)&As[0][0];                  // [64][4]  (aliased, post-loop)
  float* S2  = S1 + 64*4;                          // [64][4]
  float* MU  = S2 + 64*4;                          // [64]
  float* RSD = MU + 64;                            // [64]
  const int tid = threadIdx.x, lane = tid&63, wid = tid>>6;   // wid 0..7
  const int wm = wid>>2, wn = wid&3;   // wm: 32-row half, wn: 64-col quarter
  const int m0 = blockIdx.x*BM;
  const short* Ag = (const short*)A + (size_t)m0*K;
  const short* Wg = (const short*)W;
  f32x4 acc[2][4] = {};

  auto STAGE = [&](int k0, int buf){   // 5 global_load_lds per thread (1 A + 4 W)
    {
      int c = tid;                     // 0..511
      int row = c>>3;
      int col = (c&7) ^ (row&7);
      gload_lds16(Ag + (size_t)row*K + k0 + col*8, &As[buf][(size_t)c*8]);
    }
    #pragma unroll
    for (int jj=0;jj<4;++jj){
      int c = jj*512 + tid;            // 0..2047
      int row = c>>3;
      int col = (c&7) ^ (row&7);
      gload_lds16(Wg + (size_t)row*K + k0 + col*8, &Ws[buf][(size_t)c*8]);
    }
  };
  auto COMPUTE = [&](int cur){
    #pragma unroll
    for (int kk=0;kk<BK;kk+=32){
      short8 af[2], bfr[4];
      int kc = (kk>>3) + (lane>>4);
      #pragma unroll
      for (int ms=0;ms<2;++ms){
        int r = wm*32 + ms*16 + (lane&15);
        af[ms] = *(const short8*)&As[cur][r*BK + ((kc ^ (r&7))<<3)];
      }
      #pragma unroll
      for (int ns=0;ns<4;++ns){
        int r = wn*64 + ns*16 + (lane&15);
        bfr[ns] = *(const short8*)&Ws[cur][r*BK + ((kc ^ (r&7))<<3)];
      }
      #pragma unroll
      for (int ms=0;ms<2;++ms)
        #pragma unroll
        for (int ns=0;ns<4;++ns)
          acc[ms][ns] = __builtin_amdgcn_mfma_f32_16x16x32_bf16(af[ms], bfr[ns], acc[ms][ns], 0, 0, 0);
    }
  };

  const int NT = K/BK;              // 16 (FFN2)
  STAGE(0, 0); STAGE(BK, 1);
  WAIT_VMCNT(5);                    // t0 complete; t1's 5 stay in flight
  block_sync();
  for (int t=0;t<NT;++t){
    const int cur = t&1;
    __builtin_amdgcn_s_setprio(1);
    COMPUTE(cur);
    __builtin_amdgcn_s_setprio(0);
    block_sync();                   // all waves done reading buf cur
    if (t+2 < NT) STAGE((t+2)*BK, cur);
    if (t+1 < NT){
      if (t+2 < NT) { WAIT_VMCNT(5); }   // complete t+1, keep t+2 in flight
      else          { WAIT_VMCNT(0); }   // tail
      block_sync();
    }
  }
  // bias + residual in place
  #pragma unroll
  for (int ns=0;ns<4;++ns){
    int col = wn*64 + ns*16 + (lane&15);
    float bc = bias[col];
    #pragma unroll
    for (int ms=0;ms<2;++ms){
      int rl = wm*32 + ms*16 + ((lane>>4)<<2);
      #pragma unroll
      for (int i=0;i<4;++i){
        float v = acc[ms][ns][i] + bc;
        if (ADDRES) v += bf2f(res[(size_t)(m0+rl+i)*256 + col]);
        acc[ms][ns][i] = v;
      }
    }
  }
  // per-row partial sums over this wave's 64 cols -> LDS (aliased on As)
  #pragma unroll
  for (int ms=0;ms<2;++ms)
    #pragma unroll
    for (int i=0;i<4;++i){
      float p1 = acc[ms][0][i]+acc[ms][1][i]+acc[ms][2][i]+acc[ms][3][i];
      float p2 = acc[ms][0][i]*acc[ms][0][i] + acc[ms][1][i]*acc[ms][1][i]
               + acc[ms][2][i]*acc[ms][2][i] + acc[ms][3][i]*acc[ms][3][i];
      #pragma unroll
      for (int o=1;o<16;o<<=1){ p1 += __shfl_xor(p1,o,64); p2 += __shfl_xor(p2,o,64); }
      if ((lane&15)==0){
        int rl = wm*32 + ms*16 + ((lane>>4)<<2) + i;
        S1[rl*4 + wn] = p1; S2[rl*4 + wn] = p2;
      }
    }
  __syncthreads();
  if (tid < 64){
    float s1 = S1[tid*4+0]+S1[tid*4+1]+S1[tid*4+2]+S1[tid*4+3];
    float s2 = S2[tid*4+0]+S2[tid*4+1]+S2[tid*4+2]+S2[tid*4+3];
    float mean = s1*(1.f/256.f);
    float var = fmaxf(s2*(1.f/256.f) - mean*mean, 0.f);
    MU[tid] = mean; RSD[tid] = 1.f/sqrtf(var + 1e-5f);
  }
  __syncthreads();
  // LN -> LDS restage (tile is CONTIGUOUS 32KB in global) -> coalesced stores
  constexpr int OP = 268;
  u16* O = (u16*)&Ws[0][0];         // 64*268*2 = 34304 B, fits in Ws
  #pragma unroll
  for (int ns=0;ns<4;++ns){
    int col = wn*64 + ns*16 + (lane&15);
    float gg = g[col], bb = bv[col];
    #pragma unroll
    for (int ms=0;ms<2;++ms){
      int rl = wm*32 + ms*16 + ((lane>>4)<<2);
      #pragma unroll
      for (int i=0;i<4;++i){
        float y = (acc[ms][ns][i] - MU[rl+i])*RSD[rl+i]*gg + bb;
        if (LEAKY) y = y>0.f ? y : 0.01f*y;
        O[(rl+i)*OP + col] = f2bf(y);
        if (outf) outf[(size_t)(m0+rl+i)*256 + col] = y;
      }
    }
  }
  __syncthreads();
  u16* ob = outb + (size_t)m0*256;
  const int rr = tid>>5;            // 32 threads/row, 16 rows/pass
  const int cc = (tid&31)<<3;       // 8 u16 = 16 B per thread
  #pragma unroll
  for (int p=0;p<4;++p){
    int r = p*16 + rr;
    *reinterpret_cast<short8*>(ob + ((size_t)r<<8) + cc) =
        *reinterpret_cast<const short8*>(&O[r*OP + cc]);
  }
}

// -------- fused ring attention + WO GEMM + LN + leaky + SKV GEMM + star scores --------
// R14 = revert to R12 (session best, 1014.6us). R13's direct-to-reg WO loads caused
// 16-line address replay per instruction + 8.6MB extra FETCH -> +12us. LDS staging via
// global_load_lds is the right pattern for 512B-strided fragment loads.
__global__ __launch_bounds__(512, 4) void attn_ln(
    const u16* __restrict__ qkv, const float* __restrict__ akav,
    const u16* __restrict__ W, const float* __restrict__ bo,
    const float* __restrict__ g, const float* __restrict__ bv,
    const u16* __restrict__ Wskv, const float* __restrict__ bskv,
    const float* __restrict__ sq, float* __restrict__ sbuf,
    u16* __restrict__ svb, u16* __restrict__ outb, float* __restrict__ outf)
{
  constexpr int BK=32, NT=256/BK;   // 8 K-steps
  __shared__ __align__(16) char LB[68096];
  short* Afull = (short*)LB;                 // [64][256] u16 swizzled, 32 KB
  short* Ws2   = (short*)(LB + 32768);       // [2][256*32] u16 (WO) / [512][32] (WSKV), 32 KB
  float* S1  = (float*)(LB + 65536);         // [64][4]
  float* S2  = S1 + 256;                     // [64][4]
  float* MU  = S2 + 256;                     // [64]
  float* RSD = MU + 64;                      // [64]
  const int tid = threadIdx.x, lane = tid&63, wid = tid>>6;
  const int wm = wid>>2, wn = wid&3;         // WO GEMM: 2 row-halves x 4 col-quarters
  const int m0 = blockIdx.x*64;
  const short* Wg = (const short*)W;

  auto STAGE_W = [&](int k0, int buf){   // 2 global_load_lds per thread (WO)
    #pragma unroll
    for (int jj=0;jj<2;++jj){
      int c = jj*512 + tid;              // granule 0..1023
      int row = c>>2;                    // 0..255
      int col = (c&3) ^ (row&3);         // pre-swizzled source granule
      gload_lds16(Wg + (size_t)row*256 + k0 + col*8, &Ws2[(size_t)buf*8192 + (size_t)c*8]);
    }
  };
  auto STAGE_SKV = [&](int t){           // 4 global_load_lds per thread (WSKV chunk)
    #pragma unroll
    for (int jj=0;jj<4;++jj){            // [512 rows][4 granules], 32 KB
      int c = jj*512 + tid;
      int row = c>>2;
      int col = (c&3) ^ (row&3);
      gload_lds16((const short*)Wskv + (size_t)row*256 + t*32 + col*8, Ws2 + (size_t)c*8);
    }
  };

  // ---- issue first two WO buffers; pin them before attention's loads ----
  STAGE_W(0, 0); STAGE_W(BK, 1);
  __builtin_amdgcn_sched_barrier(0);

  // ---- phase 1: ring attention, 2 tokens/wave-pass, explicit 2-deep pipeline ----
  const int bblk = m0 >> 12;        // batch is uniform across the block (64-token tiles)
  const int j8 = lane & 31;         // channel-octet index (8 ch per lane)
  float ak[8], av[8];
  {
    const float* pa = akav + (size_t)bblk*H_ + j8*8;
    const float* pv = akav + 2048 + (size_t)bblk*H_ + j8*8;
    float4 a0 = *(const float4*)pa, a1 = *(const float4*)(pa+4);
    float4 v0 = *(const float4*)pv, v1 = *(const float4*)(pv+4);
    ak[0]=a0.x; ak[1]=a0.y; ak[2]=a0.z; ak[3]=a0.w;
    ak[4]=a1.x; ak[5]=a1.y; ak[6]=a1.z; ak[7]=a1.w;
    av[0]=v0.x; av[1]=v0.y; av[2]=v0.z; av[3]=v0.w;
    av[4]=v1.x; av[5]=v1.y; av[6]=v1.z; av[7]=v1.w;
  }
  // buffer layout: [0]=q [1]=kc [2]=vc [3]=kp [4]=vp [5]=kn [6]=vn
  auto LOADP = [&](int pp, short8* v){
    const int rl = wid*8 + pp*2 + (lane>>5);
    const size_t tok = (size_t)(m0 + rl);
    const int l = (int)(tok & (L_-1));
    v[0] = *(const short8*)(qkv + tok*768 + j8*8);
    v[1] = *(const short8*)(qkv + tok*768 + 256 + j8*8);
    v[2] = *(const short8*)(qkv + tok*768 + 512 + j8*8);
    const short8 z = {0,0,0,0,0,0,0,0};
    if (l>0){
      v[3] = *(const short8*)(qkv + (tok-1)*768 + 256 + j8*8);
      v[4] = *(const short8*)(qkv + (tok-1)*768 + 512 + j8*8);
    } else { v[3]=z; v[4]=z; }
    if (l<L_-1){
      v[5] = *(const short8*)(qkv + (tok+1)*768 + 256 + j8*8);
      v[6] = *(const short8*)(qkv + (tok+1)*768 + 512 + j8*8);
    } else { v[5]=z; v[6]=z; }
  };
  auto PASS = [&](int pp, const short8* v){
    const int rl = wid*8 + pp*2 + (lane>>5);
    float dp=0.f, dc=0.f, dn=0.f, da=0.f;
    #pragma unroll
    for (int c=0;c<8;++c){
      float qc = bf2f((u16)v[0][c]);
      dp += qc*bf2f((u16)v[3][c]);
      dc += qc*bf2f((u16)v[1][c]);
      dn += qc*bf2f((u16)v[5][c]);
      da += qc*ak[c];
    }
    #pragma unroll
    for (int o=1;o<8;o<<=1){           // reduce within the 8-lane head group
      dp += __shfl_xor(dp,o,64); dc += __shfl_xor(dc,o,64);
      dn += __shfl_xor(dn,o,64); da += __shfl_xor(da,o,64);
    }
    dp *= 0.125f; dc *= 0.125f; dn *= 0.125f; da *= 0.125f;
    float m = fmaxf(fmaxf(dp,dc), fmaxf(dn,da));
    float e0 = __expf(dp-m), e1 = __expf(dc-m), e2 = __expf(dn-m), e3 = __expf(da-m);
    float rd = 1.f/(e0+e1+e2+e3);
    short8 ov;
    #pragma unroll
    for (int c=0;c<8;++c)
      ov[c] = (short)f2bf((e0*bf2f((u16)v[4][c]) + e1*bf2f((u16)v[2][c])
                         + e2*bf2f((u16)v[6][c]) + e3*av[c])*rd);
    int s = (j8 & ~7) | ((j8&7) ^ (rl&7));
    *(short8*)&Afull[rl*256 + s*8] = ov;
  };
  {
    short8 bA[7], bB[7];
    LOADP(0, bA);
    LOADP(1, bB);
    PASS(0, bA);
    LOADP(2, bA);
    PASS(1, bB);
    LOADP(3, bB);
    PASS(2, bA);
    PASS(3, bB);
  }
  WAIT_LGKM0();                     // Afull ds_writes complete
  WAIT_VMCNT(2);                    // W buf0 ready (attention's loads already drained)
  block_sync();

  // ---- phase 2: WO GEMM, K=256 in 8 steps of BK=32 ----
  f32x4 acc[2][4] = {};
  for (int t=0;t<NT;++t){
    const int cur = t&1;
    __builtin_amdgcn_s_setprio(1);
    {
      short8 af[2], bfr[4];
      #pragma unroll
      for (int ms=0;ms<2;++ms){
        int r = wm*32 + ms*16 + (lane&15);
        int gk = t*4 + (lane>>4);
        int s = (gk & ~7) | ((gk&7) ^ (r&7));
        af[ms] = *(const short8*)&Afull[r*256 + s*8];
      }
      #pragma unroll
      for (int ns=0;ns<4;++ns){
        int r2 = wn*64 + ns*16 + (lane&15);
        int sl = (lane>>4) ^ (r2&3);
        bfr[ns] = *(const short8*)&Ws2[(size_t)cur*8192 + r2*32 + sl*8];
      }
      #pragma unroll
      for (int ms=0;ms<2;++ms)
        #pragma unroll
        for (int ns=0;ns<4;++ns)
          acc[ms][ns] = __builtin_amdgcn_mfma_f32_16x16x32_bf16(af[ms], bfr[ns], acc[ms][ns], 0, 0, 0);
    }
    __builtin_amdgcn_s_setprio(0);
    block_sync();                   // all waves done reading Ws2[cur]
    if (t+2 < NT) STAGE_W((t+2)*BK, cur);
    if (t+1 < NT){
      if (t+2 < NT) { WAIT_VMCNT(2); }   // complete t+1, keep t+2 in flight
      else          { WAIT_VMCNT(0); }   // tail
      block_sync();
    }
  }
  // Ws2 dead -> issue WSKV chunk 0 NOW; it flies across all of phase 3
  // (phase-3 syncs avoid vmcnt drains so it stays in flight).
  STAGE_SKV(0);

  // ---- phase 3: bias + LN + leaky -> Afull (swizzled) -> coalesced NB store ----
  #pragma unroll
  for (int ns=0;ns<4;++ns){
    int col = wn*64 + ns*16 + (lane&15);
    float bc = bo[col];
    #pragma unroll
    for (int ms=0;ms<2;++ms)
      #pragma unroll
      for (int i=0;i<4;++i)
        acc[ms][ns][i] += bc;
  }
  #pragma unroll
  for (int ms=0;ms<2;++ms)
    #pragma unroll
    for (int i=0;i<4;++i){
      float p1 = acc[ms][0][i]+acc[ms][1][i]+acc[ms][2][i]+acc[ms][3][i];
      float p2 = acc[ms][0][i]*acc[ms][0][i] + acc[ms][1][i]*acc[ms][1][i]
               + acc[ms][2][i]*acc[ms][2][i] + acc[ms][3][i]*acc[ms][3][i];
      #pragma unroll
      for (int o=1;o<16;o<<=1){ p1 += __shfl_xor(p1,o,64); p2 += __shfl_xor(p2,o,64); }
      if ((lane&15)==0){
        int rl = wm*32 + ms*16 + ((lane>>4)<<2) + i;
        S1[rl*4 + wn] = p1; S2[rl*4 + wn] = p2;
      }
    }
  WAIT_LGKM0(); block_sync();
  if (tid < 64){
    float s1 = S1[tid*4+0]+S1[tid*4+1]+S1[tid*4+2]+S1[tid*4+3];
    float s2 = S2[tid*4+0]+S2[tid*4+1]+S2[tid*4+2]+S2[tid*4+3];
    float mean = s1*(1.f/256.f);
    float var = fmaxf(s2*(1.f/256.f) - mean*mean, 0.f);
    MU[tid] = mean; RSD[tid] = 1.f/sqrtf(var + 1e-5f);
  }
  WAIT_LGKM0(); block_sync();
  #pragma unroll
  for (int ns=0;ns<4;++ns){
    int col = wn*64 + ns*16 + (lane&15);
    float gg = g[col], bb = bv[col];
    #pragma unroll
    for (int ms=0;ms<2;++ms){
      int rl = wm*32 + ms*16 + ((lane>>4)<<2);
      #pragma unroll
      for (int i=0;i<4;++i){
        float y = (acc[ms][ns][i] - MU[rl+i])*RSD[rl+i]*gg + bb;
        y = y>0.f ? y : 0.01f*y;
        int row = rl+i, cg = col>>3;
        int s = (cg & ~7) | ((cg&7) ^ (row&7));
        Afull[row*256 + s*8 + (col&7)] = f2bf(y);
        if (outf) outf[(size_t)(m0+row)*256 + col] = y;
      }
    }
  }
  WAIT_LGKM0(); block_sync();
  const int rr = tid>>5, cg8 = tid&31;   // 32 threads/row, 16B granule each
  {
    u16* ob = outb + (size_t)m0*256;
    #pragma unroll
    for (int p=0;p<4;++p){
      int r = p*16 + rr;
      int s = (cg8 & ~7) | ((cg8&7) ^ (r&7));
      *reinterpret_cast<short8*>(ob + ((size_t)r<<8) + cg8*8) =
          *reinterpret_cast<const short8*>(&Afull[r*256 + s*8]);
    }
  }

  // ---- phase 4: SKV GEMM (A = resident Afull, WSKV reg-stage pipelined via Ws2) ----
  // 8 N-bands of 64 cols (band = wid); bands 0-3 = K-half (scores only, never stored),
  // bands 4-7 = V-half -> SVB.
  f32x4 acc2[4][4] = {};
  for (int t=0;t<8;++t){
    WAIT_VMCNT(0);                       // chunk t landed (also drains NB stores, 1st iter)
    block_sync();
    short8 af[4], bf4[4];
    #pragma unroll
    for (int ms=0;ms<4;++ms){
      int r = ms*16 + (lane&15);
      int gk = t*4 + (lane>>4);
      int s = (gk & ~7) | ((gk&7) ^ (r&7));
      af[ms] = *(const short8*)&Afull[r*256 + s*8];
    }
    #pragma unroll
    for (int ns=0;ns<4;++ns){
      int n = wid*64 + ns*16 + (lane&15);
      int sl = (lane>>4) ^ (n&3);
      bf4[ns] = *(const short8*)&Ws2[n*32 + sl*8];
    }
    WAIT_LGKM0();                        // chunk t safely in registers
    block_sync();                        // all waves done reading Ws2
    if (t+1 < 8) STAGE_SKV(t+1);         // overwrite Ws2; latency hides under MFMA
    __builtin_amdgcn_s_setprio(1);
    #pragma unroll
    for (int ms=0;ms<4;++ms)
      #pragma unroll
      for (int ns=0;ns<4;++ns)
        acc2[ms][ns] = __builtin_amdgcn_mfma_f32_16x16x32_bf16(af[ms], bf4[ns], acc2[ms][ns], 0, 0, 0);
    __builtin_amdgcn_s_setprio(0);
  }
  // epilogue: scores (bands 0-3, f32 pre-round) / V-half restage (bands 4-7)
  u16* O2 = (u16*)LB;                    // [64][256] u16 over dead Afull (reads all done)
  if (wid < 4){
    float sqv[4], bcv[4];
    #pragma unroll
    for (int ns=0;ns<4;++ns){
      int n = wid*64 + ns*16 + (lane&15);
      sqv[ns] = sq[bblk*H_ + n];
      bcv[ns] = bskv[n];
    }
    #pragma unroll
    for (int ms=0;ms<4;++ms)
      #pragma unroll
      for (int i=0;i<4;++i){
        float p = (acc2[ms][0][i]+bcv[0])*sqv[0] + (acc2[ms][1][i]+bcv[1])*sqv[1]
                + (acc2[ms][2][i]+bcv[2])*sqv[2] + (acc2[ms][3][i]+bcv[3])*sqv[3];
        #pragma unroll
        for (int o=1;o<16;o<<=1) p += __shfl_xor(p,o,64);
        if ((lane&15)==0){
          int rl = ms*16 + ((lane>>4)<<2) + i;
          int l = (m0 + rl) & (L_-1);
          sbuf[(size_t)(bblk*4 + wid)*(L_+1) + 1 + l] = p*0.125f;
        }
      }
  } else {
    #pragma unroll
    for (int ns=0;ns<4;++ns){
      int n = wid*64 + ns*16 + (lane&15);
      float bc = bskv[n];
      #pragma unroll
      for (int ms=0;ms<4;++ms){
        int rb = ms*16 + ((lane>>4)<<2);
        #pragma unroll
        for (int i=0;i<4;++i)
          O2[(rb+i)*256 + (n-256)] = f2bf(acc2[ms][ns][i] + bc);
      }
    }
  }
  WAIT_LGKM0(); block_sync();
  // coalesced V store: 64 rows x 512 B
  u16* vb = svb + (size_t)m0*256;
  #pragma unroll
  for (int p=0;p<4;++p){
    int r = p*16 + rr;
    *reinterpret_cast<short8*>(vb + ((size_t)r<<8) + cg8*8) =
        *reinterpret_cast<const short8*>(&O2[r*256 + cg8*8]);
  }
}

// ---------------- star attention: per-row max + 1/sum (+ j=0 self-score) ----------------
__global__ __launch_bounds__(256) void star_maxsum(
    float* __restrict__ s, const float* __restrict__ sq,
    const float* __restrict__ sk0, float* __restrict__ sms)
{
  const int bh = blockIdx.x;        // b*4 + h
  const int b = bh>>2, h = bh&3;
  float* row = s + (size_t)bh*(L_+1);
  __shared__ float red[256];
  const int tid = threadIdx.x;
  // j=0 relay self-score
  float p0 = (tid < 64) ? sq[b*H_ + h*64 + tid]*sk0[b*H_ + h*64 + tid] : 0.f;
  red[tid] = p0; __syncthreads();
  for (int st=128; st>0; st>>=1){ if (tid<st) red[tid] += red[tid+st]; __syncthreads(); }
  const float s0 = red[0]*0.125f;
  if (tid==0) row[0] = s0;
  __syncthreads();
  float m = s0;
  for (int j=1+tid; j<=L_; j+=256) m = fmaxf(m, row[j]);
  red[tid] = m; __syncthreads();
  for (int st=128; st>0; st>>=1){ if (tid<st) red[tid] = fmaxf(red[tid], red[tid+st]); __syncthreads(); }
  m = red[0]; __syncthreads();
  float sum = (tid==0) ? expf(s0-m) : 0.f;
  for (int j=1+tid; j<=L_; j+=256) sum += expf(row[j]-m);
  red[tid] = sum; __syncthreads();
  for (int st=128; st>0; st>>=1){ if (tid<st) red[tid] += red[tid+st]; __syncthreads(); }
  if (tid==0){ sms[bh*2] = m; sms[bh*2+1] = 1.f/red[0]; }
}

// partial over 64-token segments, all 4 heads per block: grid = B_*64
// applies exp(s-m)*rs inline (raw scores in a); V from the dedicated SVB buffer
__global__ __launch_bounds__(256) void star_satt_part(
    const float* __restrict__ a, const float* __restrict__ sms,
    const u16* __restrict__ svb, float* __restrict__ part)
{
  const int blk = blockIdx.x;
  const int b = blk >> 6, seg = blk & 63;
  const int tid = threadIdx.x, q4 = tid & 63, sub = tid >> 6;
  const int h = q4 >> 4;
  const float* arow = a + (size_t)(b*4 + h)*(L_+1) + 1;
  const float m = sms[(b*4+h)*2], rs = sms[(b*4+h)*2+1];
  float a0=0.f,a1=0.f,a2=0.f,a3=0.f;
  const int j0 = seg*64 + sub*16;
  #pragma unroll 4
  for (int jj=j0; jj<j0+16; ++jj){
    u16x4 v = *(const u16x4*)(svb + ((size_t)b*L_ + jj)*256 + q4*4);
    float al = expf(arow[jj]-m)*rs;
    a0 += al*bf2f(v.x); a1 += al*bf2f(v.y); a2 += al*bf2f(v.z); a3 += al*bf2f(v.w);
  }
  __shared__ float red[4][256];
  red[sub][q4*4+0]=a0; red[sub][q4*4+1]=a1; red[sub][q4*4+2]=a2; red[sub][q4*4+3]=a3;
  __syncthreads();
  if (sub==0){
    #pragma unroll
    for (int c=0;c<4;++c){
      int ch = q4*4+c;
      part[(size_t)blk*256 + ch] = red[0][ch]+red[1][ch]+red[2][ch]+red[3][ch];
    }
  }
}

// ---------------- relay weight transpose pack ----------------
__global__ __launch_bounds__(256) void pack_wT(
    const float* __restrict__ w0, const float* __restrict__ w1,
    const float* __restrict__ w2, const float* __restrict__ w3,
    const float* __restrict__ w4, const float* __restrict__ w5,
    float* __restrict__ T)
{
  __shared__ float tile[32][33];
  const int blk = blockIdx.x;           // NL*6*64
  const int t = blk & 63, m = blk >> 6;
  const int l = m / 6, w = m % 6;
  const float* srcs[6] = {w0, w1, w2, w3, w4, w5};
  const float* src = srcs[w] + (size_t)l*65536;
  const int r0 = (t>>3)*32, c0 = (t&7)*32;
  const int rr = threadIdx.x >> 5, cc = threadIdx.x & 31;   // 8 rows/pass
  #pragma unroll
  for (int p=0;p<4;++p)
    tile[rr + p*8][cc] = src[(size_t)(r0 + rr + p*8)*256 + c0 + cc];
  __syncthreads();
  float* dst = T + (size_t)m*65536;
  #pragma unroll
  for (int p=0;p<4;++p)
    dst[(size_t)(c0 + rr + p*8)*256 + r0 + cc] = tile[cc][rr + p*8];
}

// ---------------- tiny relay projections (transposed f32 weights, coalesced) ----------------
struct TPB { const float* b; float* out; };
struct TPB5 { TPB p[5]; };
__global__ __launch_bounds__(256) void relay_projs(
    const float* __restrict__ relay, const float* __restrict__ TW, TPB5 tp)
{
  const int b = blockIdx.x, w = blockIdx.y, n = threadIdx.x;
  __shared__ float rs[H_];
  rs[n] = relay[b*H_ + n];
  __syncthreads();
  const float* wt = TW + (size_t)w*65536;
  float s = tp.p[w].b[n];
  #pragma unroll 8
  for (int c=0;c<H_;++c) s += rs[c]*wt[(size_t)c*256 + n];
  tp.p[w].out[b*H_+n] = s;
}

// ---------------- relay tail: satt combine + star W_o matvec (transposed) + leaky ----------------
__global__ __launch_bounds__(256) void relay_tail_k(
    const float* __restrict__ part, const float* __restrict__ a,
    const float* __restrict__ sms, const float* __restrict__ sv0,
    const float* __restrict__ TW, const float* __restrict__ bo,
    float* __restrict__ relay, float* __restrict__ outr)
{
  const int b = blockIdx.x, n = threadIdx.x;
  __shared__ float rs[H_];
  const int h = n >> 6;
  const float m = sms[(b*4+h)*2], rsum = sms[(b*4+h)*2+1];
  float a0 = expf(a[(size_t)(b*4+h)*(L_+1)] - m)*rsum;
  float s = a0 * sv0[b*H_ + n];
  #pragma unroll 8
  for (int g2=0; g2<64; ++g2) s += part[((size_t)b*64+g2)*256 + n];
  rs[n] = s;
  __syncthreads();
  const float* wt = TW + (size_t)5*65536;   // star_wo slot
  float v = bo[n];
  #pragma unroll 8
  for (int c=0;c<H_;++c) v += rs[c]*wt[(size_t)c*256 + n];
  v = v>0.f ? v : 0.01f*v;
  relay[b*H_+n] = v;
  if (outr) outr[b*H_+n] = v;
}

// ---------------- setup kernels ----------------
__global__ void f32_to_bf16_k(const float* __restrict__ s, u16* __restrict__ d, int n){
  for (int i = blockIdx.x*blockDim.x + threadIdx.x; i < n; i += gridDim.x*blockDim.x)
    d[i] = f2bf(s[i]);
}
__global__ void pack_wqkv(const float* __restrict__ wq, const float* __restrict__ wk,
                          const float* __restrict__ wv, u16* __restrict__ dst){
  const int n = NL_*768*H_;
  for (int i = blockIdx.x*blockDim.x + threadIdx.x; i < n; i += gridDim.x*blockDim.x){
    int l = i/(768*H_); int rem = i%(768*H_); int r = rem/H_; int c = rem%H_;
    float v = (r<256) ? wq[((size_t)l*H_ + r)*H_ + c]
            : (r<512) ? wk[((size_t)l*H_ + (r-256))*H_ + c]
                      : wv[((size_t)l*H_ + (r-512))*H_ + c];
    dst[i] = f2bf(v);
  }
}
__global__ void pack_wskv(const float* __restrict__ wk, const float* __restrict__ wv, u16* __restrict__ dst){
  const int n = NL_*512*H_;
  for (int i = blockIdx.x*blockDim.x + threadIdx.x; i < n; i += gridDim.x*blockDim.x){
    int l = i/(512*H_); int rem = i%(512*H_); int r = rem/H_; int c = rem%H_;
    float v = (r<256) ? wk[((size_t)l*H_ + r)*H_ + c]
                      : wv[((size_t)l*H_ + (r-256))*H_ + c];
    dst[i] = f2bf(v);
  }
}
__global__ void pack_biases(const float* __restrict__ bq, const float* __restrict__ bk,
                            const float* __restrict__ bv, float* __restrict__ dqkv,
                            const float* __restrict__ sbk, const float* __restrict__ sbv,
                            float* __restrict__ dskv){
  int i = blockIdx.x*blockDim.x + threadIdx.x;
  if (i < NL_*768){
    int l = i/768, r = i%768;
    dqkv[i] = (r<256) ? bq[l*H_+r] : (r<512) ? bk[l*H_+r-256] : bv[l*H_+r-512];
  }
  if (i < NL_*512){
    int l = i/512, r = i%512;
    dskv[i] = (r<256) ? sbk[l*H_+r] : sbv[l*H_+r-256];
  }
}
__global__ void init_nodes(const float* __restrict__ data, const float* __restrict__ pos, u16* __restrict__ nodes){
  const int total = TOK_*H_/4;
  int i = blockIdx.x*blockDim.x + threadIdx.x;
  if (i >= total) return;
  float4 d = ((const float4*)data)[i];
  float4 p = ((const float4*)pos)[i % (L_*H_/4)];
  u16x4 o; o.x=f2bf(d.x+p.x); o.y=f2bf(d.y+p.y); o.z=f2bf(d.z+p.z); o.w=f2bf(d.w+p.w);
  ((u16x4*)nodes)[i] = o;
}
__global__ void relay_partial(const float* __restrict__ data, const float* __restrict__ pos, float* __restrict__ part){
  const int b = blockIdx.x>>3, seg = blockIdx.x&7, hh = threadIdx.x;
  float s = 0.f;
  for (int l = seg*512; l < seg*512+512; ++l)
    s += data[((size_t)b*L_ + l)*H_ + hh] + pos[(size_t)l*H_ + hh];
  part[blockIdx.x*H_ + hh] = s;
}
__global__ void relay_combine(const float* __restrict__ part, float* __restrict__ relay){
  const int b = blockIdx.x, hh = threadIdx.x;
  float s = 0.f;
  for (int g=0; g<8; ++g) s += part[(b*8+g)*H_ + hh];
  relay[b*H_+hh] = s * (1.0f/L_);
}

extern "C" void kernel_launch(void* const* d_in, const int* in_sizes, int n_in,
                              void* d_out, int out_size, void* d_ws, size_t ws_size,
                              hipStream_t stream)
{
  const float* data   = (const float*)d_in[0];
  const float* pos    = (const float*)d_in[2];
  const float* ln_g   = (const float*)d_in[3];
  const float* ln_b   = (const float*)d_in[4];
  const float* ff_w1  = (const float*)d_in[5];
  const float* ff_b1  = (const float*)d_in[6];
  const float* ff_w2  = (const float*)d_in[7];
  const float* ff_b2  = (const float*)d_in[8];
  const float* ff_lng = (const float*)d_in[9];
  const float* ff_lnb = (const float*)d_in[10];
  const float* ring_wq= (const float*)d_in[11]; const float* ring_bq= (const float*)d_in[12];
  const float* ring_wk= (const float*)d_in[13]; const float* ring_bk= (const float*)d_in[14];
  const float* ring_wv= (const float*)d_in[15]; const float* ring_bv= (const float*)d_in[16];
  const float* ring_wo= (const float*)d_in[17]; const float* ring_bo= (const float*)d_in[18];
  const float* star_wq= (const float*)d_in[19]; const float* star_bq= (const float*)d_in[20];
  const float* star_wk= (const float*)d_in[21]; const float* star_bk= (const float*)d_in[22];
  const float* star_wv= (const float*)d_in[23]; const float* star_bv= (const float*)d_in[24];
  const float* star_wo= (const float*)d_in[25]; const float* star_bo= (const float*)d_in[26];

  char* ws = (char*)d_ws;
  size_t off = 0;
  auto alc = [&](size_t n){ size_t cur = off; off = (cur + n + 255) & ~(size_t)255; return (void*)(ws + cur); };
  u16*  W1B   = (u16*)alc((size_t)NL_*DI_*H_*2);
  u16*  W2B   = (u16*)alc((size_t)NL_*H_*DI_*2);
  u16*  WQKVB = (u16*)alc((size_t)NL_*768*H_*2);
  u16*  WOB   = (u16*)alc((size_t)NL_*H_*H_*2);
  u16*  WSKVB = (u16*)alc((size_t)NL_*512*H_*2);
  float* BQKVB= (float*)alc((size_t)NL_*768*4);
  float* BSKVB= (float*)alc((size_t)NL_*512*4);
  float* TWB  = (float*)alc((size_t)NL_*6*H_*H_*4);   // transposed relay weights, 9.4 MB
  u16*  NB    = (u16*)alc((size_t)TOK_*H_*2);
  u16*  HB    = (u16*)alc((size_t)TOK_*H_*2);
  u16*  T1R   = (u16*)alc((size_t)TOK_*DI_*2);   // aliased: T1 | QKV
  u16*  SVB   = (u16*)alc((size_t)TOK_*256*2);   // star V (dedicated: attn_ln writes while reading QKV)
  float* RELAY  = (float*)alc(B_*H_*4);
  float* PART   = (float*)alc(64*H_*4);
  float* AKAV   = (float*)alc(2*B_*H_*4);
  float* SQB    = (float*)alc(B_*H_*4);
  float* SK0B   = (float*)alc(B_*H_*4);
  float* SV0B   = (float*)alc(B_*H_*4);
  float* SBUF   = (float*)alc((size_t)B_*NH_*(L_+1)*4);
  float* SMS    = (float*)alc((size_t)B_*NH_*2*4);
  float* SPART  = (float*)alc((size_t)B_*64*256*4);
  u16* QKVB = T1R;

  // weight conversion / packing (deterministic, every call)
  f32_to_bf16_k<<<2048, 256, 0, stream>>>(ff_w1, W1B, NL_*DI_*H_);
  f32_to_bf16_k<<<2048, 256, 0, stream>>>(ff_w2, W2B, NL_*H_*DI_);
  f32_to_bf16_k<<<1024, 256, 0, stream>>>(ring_wo, WOB, NL_*H_*H_);
  pack_wqkv<<<2048, 256, 0, stream>>>(ring_wq, ring_wk, ring_wv, WQKVB);
  pack_wskv<<<2048, 256, 0, stream>>>(star_wk, star_wv, WSKVB);
  pack_biases<<<18, 256, 0, stream>>>(ring_bq, ring_bk, ring_bv, BQKVB, star_bk, star_bv, BSKVB);
  pack_wT<<<NL_*6*64, 256, 0, stream>>>(ring_wk, ring_wv, star_wq, star_wk, star_wv, star_wo, TWB);

  init_nodes<<<(TOK_*H_/4 + 255)/256, 256, 0, stream>>>(data, pos, NB);
  relay_partial<<<64, 256, 0, stream>>>(data, pos, PART);
  relay_combine<<<B_, 256, 0, stream>>>(PART, RELAY);

  for (int l=0; l<NL_; ++l){
    const float* TWl = TWB + (size_t)l*6*H_*H_;
    // FFN1: relu(NB @ W1^T + b1) -> T1R
    gemm_bt<true,true><<<(DI_/128)*(TOK_/128), 512, 0, stream>>>(
        NB, W1B + (size_t)l*DI_*H_, ff_b1 + l*DI_, T1R, DI_, H_, DI_/128);
    // FFN2 + residual(NB) + LN -> HB
    gemm_ln<true,false><<<TOK_/64, 512, 0, stream>>>(
        T1R, W2B + (size_t)l*H_*DI_, ff_b2 + l*H_, NB,
        ff_lng + l*H_, ff_lnb + l*H_, HB, nullptr, DI_);
    // relay-dependent small projections (relay from previous layer; coalesced TW reads)
    TPB5 tp;
    tp.p[0] = { ring_bk + l*H_, AKAV };
    tp.p[1] = { ring_bv + l*H_, AKAV + 2048 };
    tp.p[2] = { star_bq + l*H_, SQB };
    tp.p[3] = { star_bk + l*H_, SK0B };
    tp.p[4] = { star_bv + l*H_, SV0B };
    relay_projs<<<dim3(B_,5), 256, 0, stream>>>(RELAY, TWl, tp);
    // ring QKV projection
    gemm_bt<false,true><<<(768/128)*(TOK_/128), 512, 0, stream>>>(
        HB, WQKVB + (size_t)l*768*H_, BQKVB + l*768, QKVB, 768, H_, 768/128);
    // fused: ring attention + WO + LN + leaky -> NB; SKV GEMM -> scores + V-half
    attn_ln<<<TOK_/64, 512, 0, stream>>>(
        QKVB, AKAV, WOB + (size_t)l*H_*H_, ring_bo + l*H_,
        ln_g + l*H_, ln_b + l*H_,
        WSKVB + (size_t)l*512*H_, BSKVB + l*512,
        SQB, SBUF, SVB, NB,
        (l==NL_-1) ? (float*)d_out : nullptr);
    // per-row max + 1/sum (+ relay self-score) -> SMS, SBUF[.,0]
    star_maxsum<<<B_*NH_, 256, 0, stream>>>(SBUF, SQB, SK0B, SMS);
    star_satt_part<<<B_*64, 256, 0, stream>>>(SBUF, SMS, SVB, SPART);
    // satt combine + star W_o matvec + leaky -> RELAY (+f32 d_out at last layer)
    relay_tail_k<<<B_, 256, 0, stream>>>(SPART, SBUF, SMS, SV0B, TWl,
        star_bo + l*H_, RELAY,
        (l==NL_-1) ? ((float*)d_out + (size_t)TOK_*H_) : nullptr);
  }
}